// Round 2
// baseline (78.120 us; speedup 1.0000x reference)
//
#include <hip/hip_runtime.h>
#include <math.h>

// L=13, M=12, ODD_KS=(1,3,5) -> NK=3
// 4-way reduction split per output: role = tid>>6 (one wave per role).
//   role0: B/A table, d in [0,13)    role1: B/A table, d in [13,25)
//   role2: C   table, d in [0,12)    role3: C   table, d in [12,24)
// 64 outputs/block -> grid 2048 blocks (8 blocks/CU, up to 32 waves/CU),
// ~250 FMAs/thread (vs ~975) -> attacks the latency/occupancy hypothesis.
#define LL    13
#define MM    12
#define NKK   3
#define OUTS  64                  // outputs per block
#define BLOCK 256                 // 4 waves = 4 roles
#define HALO  24
#define WIN   (OUTS + 2*HALO)     // 112 staged samples
#define NWB   (25 * LL)           // B/A quads, d-major (d in [0,24], A at m==12)
#define NWC   (24 * LL)           // C quads, d-major (d in [0,23], m<12)

__shared__ float4 sP[WIN];        // {a, a^3, a^5, 0}
__shared__ float2 sZ[WIN];        // {re, im}
__shared__ float4 sWB[NWB];       // B/A coefficient quads (broadcast reads)
__shared__ float4 sWC[NWC];       // C coefficient quads
__shared__ float2 sAcc[4][OUTS];  // per-role partial sums

// Conv half: accumulate c[l] += w(d,l) . powers(o + POFS + d) over d in [D0,D1).
// Mask m in [0,12] folds at compile time; invalid slots are staged as zero.
template<int D0, int D1, int POFS>
__device__ __forceinline__ void conv_half(const float4* __restrict__ sW,
                                          int o, float c[LL])
{
    #pragma unroll
    for (int d = D0; d < D1; ++d) {
        const float4 p = sP[o + POFS + d];
        #pragma unroll
        for (int l = 0; l < LL; ++l) {
            const int m = d - l;
            if (m >= 0 && m <= MM) {            // compile-time fold
                const float4 w = sW[d * LL + l];
                c[l] += w.x * p.x + w.y * p.y + w.z * p.z;
            }
        }
    }
}

__global__ __launch_bounds__(BLOCK)
void gmp_kernel(const float* __restrict__ x,    // (B,T,2)
                const float* __restrict__ Ac,   // (L,NK)
                const float* __restrict__ Bc,   // (L,M,NK)
                const float* __restrict__ Cc,   // (L,M,NK)
                float* __restrict__ out,        // (B,T,2)
                int T, int tilesPerB)
{
    const int tid = threadIdx.x;
    const int b   = blockIdx.x / tilesPerB;
    const int t0  = (blockIdx.x % tilesPerB) * OUTS;

    const float* xb = x + (size_t)b * T * 2;

    // --- Stage 112-sample window (circular wrap); powers computed once ---
    if (tid < WIN) {
        int t = t0 - HALO + tid;
        if (t < 0)  t += T;
        if (t >= T) t -= T;
        const float2 z = *(const float2*)(xb + 2 * t);
        float a2 = z.x * z.x + z.y * z.y;
        float a  = sqrtf(a2);
        sZ[tid] = z;
        sP[tid] = make_float4(a, a * a2, a * a2 * a2, 0.0f);
    }

    // --- Stage coefficient tables (d-major quads; invalid slots = 0) ---
    for (int idx = tid; idx < NWB; idx += BLOCK) {
        const int d = idx / LL;
        const int l = idx - d * LL;
        const int m = d - l;
        float4 w = make_float4(0.f, 0.f, 0.f, 0.f);
        if (m >= 0 && m <= MM) {
            const float* s = (m == MM) ? (Ac + l * NKK)
                                       : (Bc + (l * MM + m) * NKK);
            w = make_float4(s[0], s[1], s[2], 0.f);
        }
        sWB[idx] = w;
    }
    for (int idx = tid; idx < NWC; idx += BLOCK) {
        const int d = idx / LL;
        const int l = idx - d * LL;
        const int m = d - l;
        float4 w = make_float4(0.f, 0.f, 0.f, 0.f);
        if (m >= 0 && m < MM) {
            const float* s = Cc + (l * MM + m) * NKK;
            w = make_float4(s[0], s[1], s[2], 0.f);
        }
        sWC[idx] = w;
    }
    __syncthreads();

    // --- Each wave computes one quarter of the reduction for 64 outputs ---
    const int o    = tid & 63;
    const int role = tid >> 6;

    float c[LL];
    #pragma unroll
    for (int l = 0; l < LL; ++l) c[l] = 0.f;

    if      (role == 0) conv_half< 0, 13,  0>(sWB, o, c);
    else if (role == 1) conv_half<13, 25,  0>(sWB, o, c);
    else if (role == 2) conv_half< 0, 12, 24>(sWC, o, c);
    else                conv_half<12, 24, 24>(sWC, o, c);

    // Partial epilogue: roles 0/1 weight by x1 (ofs 12), roles 2/3 by x3last (ofs 36)
    const int zofs = (role < 2) ? 12 : 36;
    float sr = 0.f, si = 0.f;
    #pragma unroll
    for (int l = 0; l < LL; ++l) {
        const float2 z = sZ[o + l + zofs];
        sr += z.x * c[l];
        si += z.y * c[l];
    }
    sAcc[role][o] = make_float2(sr, si);
    __syncthreads();

    // --- Wave 0 combines 4 partials and stores ---
    if (tid < OUTS) {
        const float2 a0 = sAcc[0][tid];
        const float2 a1 = sAcc[1][tid];
        const float2 a2 = sAcc[2][tid];
        const float2 a3 = sAcc[3][tid];
        const int t = t0 + tid;
        if (t < T) {
            float2* op = (float2*)(out + ((size_t)b * T + t) * 2);
            *op = make_float2(a0.x + a1.x + a2.x + a3.x,
                              a0.y + a1.y + a2.y + a3.y);
        }
    }
}

extern "C" void kernel_launch(void* const* d_in, const int* in_sizes, int n_in,
                              void* d_out, int out_size, void* d_ws, size_t ws_size,
                              hipStream_t stream)
{
    // Inputs: x (B,T,2) f32, h_0 (B,16) f32 [unused], A_kl (L,NK),
    // B_klm (L,M,NK), C_klm (L,M,NK)
    const float* x  = (const float*)d_in[0];
    const float* Ac = (const float*)d_in[2];
    const float* Bc = (const float*)d_in[3];
    const float* Cc = (const float*)d_in[4];
    float* out = (float*)d_out;

    const int Bsz = in_sizes[1] / 16;               // h_0 is (B,16)
    const int T   = in_sizes[0] / (2 * Bsz);        // x is (B,T,2)
    const int tilesPerB = (T + OUTS - 1) / OUTS;    // 128 for T=8192

    dim3 grid(Bsz * tilesPerB);                     // 2048 blocks
    dim3 block(BLOCK);
    gmp_kernel<<<grid, block, 0, stream>>>(x, Ac, Bc, Cc, out, T, tilesPerB);
}